// Round 5
// baseline (504.969 us; speedup 1.0000x reference)
//
#include <hip/hip_runtime.h>

#define HD   64
#define NB   4
#define PROJ 256   // HD * NB columns
#define SCAN_BLK 1024
#define GN   32    // dst nodes per gather block

typedef __attribute__((ext_vector_type(8))) short bf16x8;
typedef __attribute__((ext_vector_type(4))) float f32x4;

__device__ __forceinline__ float bf2f(unsigned short u) {
    union { unsigned int i; float f; } c; c.i = ((unsigned int)u) << 16; return c.f;
}
__device__ __forceinline__ unsigned short f2bf(float f) {
    union { float f; unsigned int i; } c; c.f = f;
    unsigned int r = c.i + 0x7FFF + ((c.i >> 16) & 1);   // round-to-nearest-even
    return (unsigned short)(r >> 16);
}

// ---- W pre-pack: A-operand fragments for the swapped MFMA ----
__global__ __launch_bounds__(256) void wpack_kernel(
    const float* __restrict__ Vl, unsigned short* __restrict__ wpack) {
    int t = threadIdx.x;
#pragma unroll
    for (int i = 0; i < 8; ++i) {
        int s = t + i * 256;            // 0..2047 lane-slots
        int lane = s & 63;
        int ksct = s >> 6;
        int ks = ksct & 1, ct = ksct >> 1;
        int c = ct * 16 + (lane & 15);
        int o = c >> 2, b = c & 3;
        unsigned int w[4];
#pragma unroll
        for (int j = 0; j < 4; ++j) {
            int k0 = ks * 32 + ((lane >> 4) & 3) * 8 + 2 * j;
            unsigned short lo = f2bf(Vl[((size_t)b * HD + k0) * HD + o]);
            unsigned short hi = f2bf(Vl[((size_t)b * HD + k0 + 1) * HD + o]);
            w[j] = (unsigned)lo | ((unsigned)hi << 16);
        }
        uint4 st = make_uint4(w[0], w[1], w[2], w[3]);
        *(uint4*)(wpack + (size_t)s * 8) = st;
    }
}

// ---- MFMA projection: xb[n][c] (bf16) = sum_k f[n][k] * W[k][c] ----
#define FS_STRIDE 72
__global__ __launch_bounds__(256, 4) void proj_mfma_kernel(
    const float* __restrict__ f, const unsigned short* __restrict__ wpack,
    unsigned short* __restrict__ xb, int n_nodes) {
    __shared__ unsigned short fs[64 * FS_STRIDE];
    int t = threadIdx.x;
    int lane = t & 63;
    int wt = t >> 6;
    int n0 = blockIdx.x * 64;

#pragma unroll
    for (int i = 0; i < 4; ++i) {
        int idx = t + i * 256;
        int node = idx >> 4;
        int kg = idx & 15;
        unsigned int lo = 0, hi = 0;
        if (n0 + node < n_nodes) {
            float4 v = *(const float4*)(f + ((size_t)(n0 + node) * HD + kg * 4));
            lo = (unsigned)f2bf(v.x) | ((unsigned)f2bf(v.y) << 16);
            hi = (unsigned)f2bf(v.z) | ((unsigned)f2bf(v.w) << 16);
        }
        *(uint2*)(fs + node * FS_STRIDE + kg * 4) = make_uint2(lo, hi);
    }
    __syncthreads();

    bf16x8 bfr[2];
#pragma unroll
    for (int ks = 0; ks < 2; ++ks) {
        int off = (wt * 16 + (lane & 15)) * FS_STRIDE + ks * 32 + ((lane >> 4) & 3) * 8;
        bfr[ks] = *reinterpret_cast<const bf16x8*>(&fs[off]);
    }

    f32x4 acc[16];
#pragma unroll
    for (int ct = 0; ct < 16; ++ct) acc[ct] = (f32x4){0.f, 0.f, 0.f, 0.f};

#pragma unroll
    for (int ct = 0; ct < 16; ++ct) {
#pragma unroll
        for (int ks = 0; ks < 2; ++ks) {
            bf16x8 a = *reinterpret_cast<const bf16x8*>(
                wpack + ((size_t)(ct * 2 + ks) * 64 + lane) * 8);
            acc[ct] = __builtin_amdgcn_mfma_f32_16x16x32_bf16(a, bfr[ks], acc[ct], 0, 0, 0);
        }
    }

    int node = n0 + wt * 16 + (lane & 15);
    if (node < n_nodes) {
#pragma unroll
        for (int ct = 0; ct < 16; ++ct) {
            int c0 = ct * 16 + ((lane >> 4) & 3) * 4;
            unsigned int lo = (unsigned)f2bf(acc[ct][0]) | ((unsigned)f2bf(acc[ct][1]) << 16);
            unsigned int hi = (unsigned)f2bf(acc[ct][2]) | ((unsigned)f2bf(acc[ct][3]) << 16);
            *(uint2*)(xb + (size_t)node * PROJ + c0) = make_uint2(lo, hi);
        }
    }
}

// ---- CSR build: histogram -> exclusive scan -> scatter ----

__global__ __launch_bounds__(256) void hist_kernel(
    const int* __restrict__ dst, int* __restrict__ cnt, int n_edges) {
    int e = blockIdx.x * 256 + threadIdx.x;
    if (e < n_edges) atomicAdd(&cnt[dst[e]], 1);
}

__global__ __launch_bounds__(256) void scan_a_kernel(
    const int* __restrict__ cnt, int* __restrict__ offs,
    int* __restrict__ bsum, int n) {
    __shared__ int sd[256];
    int t = threadIdx.x;
    int base = blockIdx.x * SCAN_BLK + t * 4;
    int v[4];
#pragma unroll
    for (int j = 0; j < 4; ++j) v[j] = (base + j < n) ? cnt[base + j] : 0;
    int s = v[0] + v[1] + v[2] + v[3];
    sd[t] = s; __syncthreads();
    for (int off = 1; off < 256; off <<= 1) {
        int x = (t >= off) ? sd[t - off] : 0;
        __syncthreads();
        sd[t] += x;
        __syncthreads();
    }
    int excl = sd[t] - s;
    if (t == 255) bsum[blockIdx.x] = sd[t];
    int run = excl;
#pragma unroll
    for (int j = 0; j < 4; ++j) {
        if (base + j < n) offs[base + j] = run;
        run += v[j];
    }
}

__global__ __launch_bounds__(256) void scan_b_kernel(int* __restrict__ bsum, int nblk) {
    __shared__ int sd[256];
    int t = threadIdx.x;
    int s = (t < nblk) ? bsum[t] : 0;
    sd[t] = s; __syncthreads();
    for (int off = 1; off < 256; off <<= 1) {
        int x = (t >= off) ? sd[t - off] : 0;
        __syncthreads();
        sd[t] += x;
        __syncthreads();
    }
    if (t < nblk) bsum[t] = sd[t] - s;
}

__global__ __launch_bounds__(256) void scan_c_kernel(
    int* __restrict__ offs, int* __restrict__ cursor,
    const int* __restrict__ bsum, int n) {
    int i = blockIdx.x * 256 + threadIdx.x;
    if (i < n) {
        int v = offs[i] + bsum[i / SCAN_BLK];
        offs[i] = v;
        cursor[i] = v;
    }
}

// pack {src(0:19) | etype(20:24) | dst&31(25:29), norm_bits}
__global__ __launch_bounds__(256) void scatter_kernel(
    const int* __restrict__ src, const int* __restrict__ dst,
    const int* __restrict__ etype, const float* __restrict__ norm,
    int* __restrict__ cursor, uint2* __restrict__ rec, int n_edges) {
    int e = blockIdx.x * 256 + threadIdx.x;
    if (e >= n_edges) return;
    int d = dst[e];
    int pos = atomicAdd(&cursor[d], 1);
    uint2 rr;
    rr.x = (unsigned)src[e] | ((unsigned)etype[e] << 20) | ((unsigned)(d & (GN - 1)) << 25);
    rr.y = __float_as_uint(norm[e]);
    rec[pos] = rr;
}

// ---- edge-parallel gather: block owns GN dsts, LDS f32 accumulate ----
__global__ __launch_bounds__(256) void gather_kernel(
    const uint2* __restrict__ rec, const int* __restrict__ offs,
    const unsigned short* __restrict__ xb,
    const float* __restrict__ comp_l, const float* __restrict__ bias_l,
    const float* __restrict__ f, float* __restrict__ out,
    int n_nodes, int n_edges) {
    __shared__ float hacc[GN * HD];
    int t = threadIdx.x;
    int w = t >> 6;
    int lane = t & 63;
    int d0 = blockIdx.x * GN;

#pragma unroll
    for (int j = 0; j < (GN * HD) / 256; ++j) hacc[t + j * 256] = 0.f;

    int estart = offs[d0];
    int dend = d0 + GN;
    int eend = (dend < n_nodes) ? offs[dend] : n_edges;
    int ecnt = eend - estart;
    const uint2* r = rec + estart;
    __syncthreads();

    int k = w;
    for (; k + 12 < ecnt; k += 16) {
        uint2 q0 = r[k], q1 = r[k + 4], q2 = r[k + 8], q3 = r[k + 12];
        ushort4 v0 = ((const ushort4*)(xb + (size_t)(q0.x & 0xFFFFF) * PROJ))[lane];
        ushort4 v1 = ((const ushort4*)(xb + (size_t)(q1.x & 0xFFFFF) * PROJ))[lane];
        ushort4 v2 = ((const ushort4*)(xb + (size_t)(q2.x & 0xFFFFF) * PROJ))[lane];
        ushort4 v3 = ((const ushort4*)(xb + (size_t)(q3.x & 0xFFFFF) * PROJ))[lane];
        float4 c0 = *(const float4*)(comp_l + ((q0.x >> 20) & 31) * NB);
        float4 c1 = *(const float4*)(comp_l + ((q1.x >> 20) & 31) * NB);
        float4 c2 = *(const float4*)(comp_l + ((q2.x >> 20) & 31) * NB);
        float4 c3 = *(const float4*)(comp_l + ((q3.x >> 20) & 31) * NB);
        float m0 = __uint_as_float(q0.y) * (c0.x*bf2f(v0.x) + c0.y*bf2f(v0.y) + c0.z*bf2f(v0.z) + c0.w*bf2f(v0.w));
        float m1 = __uint_as_float(q1.y) * (c1.x*bf2f(v1.x) + c1.y*bf2f(v1.y) + c1.z*bf2f(v1.z) + c1.w*bf2f(v1.w));
        float m2 = __uint_as_float(q2.y) * (c2.x*bf2f(v2.x) + c2.y*bf2f(v2.y) + c2.z*bf2f(v2.z) + c2.w*bf2f(v2.w));
        float m3 = __uint_as_float(q3.y) * (c3.x*bf2f(v3.x) + c3.y*bf2f(v3.y) + c3.z*bf2f(v3.z) + c3.w*bf2f(v3.w));
        atomicAdd(&hacc[((q0.x >> 25) & 31) * HD + lane], m0);
        atomicAdd(&hacc[((q1.x >> 25) & 31) * HD + lane], m1);
        atomicAdd(&hacc[((q2.x >> 25) & 31) * HD + lane], m2);
        atomicAdd(&hacc[((q3.x >> 25) & 31) * HD + lane], m3);
    }
    for (; k < ecnt; k += 4) {
        uint2 q = r[k];
        ushort4 v = ((const ushort4*)(xb + (size_t)(q.x & 0xFFFFF) * PROJ))[lane];
        float4 c = *(const float4*)(comp_l + ((q.x >> 20) & 31) * NB);
        float m = __uint_as_float(q.y) * (c.x*bf2f(v.x) + c.y*bf2f(v.y) + c.z*bf2f(v.z) + c.w*bf2f(v.w));
        atomicAdd(&hacc[((q.x >> 25) & 31) * HD + lane], m);
    }
    __syncthreads();

    // epilogue: bias + relu + skip, plain coalesced stores (block owns its dsts)
    float bv = bias_l[lane];
#pragma unroll
    for (int j = 0; j < (GN * HD) / 256; ++j) {
        int slot = t + j * 256;
        int node = d0 + (slot >> 6);
        if (node < n_nodes) {
            size_t o = (size_t)node * HD + lane;
            out[o] = fmaxf(hacc[slot] + bv, 0.f) + f[o];
        }
    }
}

extern "C" void kernel_launch(void* const* d_in, const int* in_sizes, int n_in,
                              void* d_out, int out_size, void* d_ws, size_t ws_size,
                              hipStream_t stream) {
    const float* features = (const float*)d_in[0];
    const float* norm     = (const float*)d_in[1];
    const float* V        = (const float*)d_in[2];
    const float* comp     = (const float*)d_in[3];
    const float* bias     = (const float*)d_in[4];
    const int*   src      = (const int*)d_in[5];
    const int*   dst      = (const int*)d_in[6];
    const int*   etype    = (const int*)d_in[7];
    float* out = (float*)d_out;

    int n_nodes = in_sizes[0] / HD;
    int n_edges = in_sizes[5];
    int L       = in_sizes[2] / (NB * HD * HD);   // N_HID
    int l       = L - 1;                          // only the last layer survives
    int comp_stride = in_sizes[3] / L;            // NUM_RELS * NB

    const float* Vl     = V    + (size_t)l * NB * HD * HD;
    const float* comp_l = comp + (size_t)l * comp_stride;
    const float* bias_l = bias + (size_t)l * HD;

    // workspace carve-up
    char* ws = (char*)d_ws;
    unsigned short* xb = (unsigned short*)ws;                 // bf16 [n_nodes, 256]
    size_t off = (size_t)n_nodes * PROJ * sizeof(unsigned short);
    int* cnt    = (int*)(ws + off);  off += (size_t)n_nodes * sizeof(int);
    int* offs   = (int*)(ws + off);  off += (size_t)n_nodes * sizeof(int);
    int* cursor = (int*)(ws + off);  off += (size_t)n_nodes * sizeof(int);
    int* bsum   = (int*)(ws + off);  off += 1024 * sizeof(int);
    unsigned short* wpack = (unsigned short*)(ws + off); off += 2048 * 8 * sizeof(unsigned short);
    off = (off + 7) & ~(size_t)7;
    uint2* rec  = (uint2*)(ws + off);                         // [n_edges]

    hipMemsetAsync(cnt, 0, (size_t)n_nodes * sizeof(int), stream);

    wpack_kernel<<<1, 256, 0, stream>>>(Vl, wpack);
    proj_mfma_kernel<<<(n_nodes + 63) / 64, 256, 0, stream>>>(features, wpack, xb, n_nodes);

    int eblocks = (n_edges + 255) / 256;
    hist_kernel<<<eblocks, 256, 0, stream>>>(dst, cnt, n_edges);

    int nblk = (n_nodes + SCAN_BLK - 1) / SCAN_BLK;           // <= 256
    scan_a_kernel<<<nblk, 256, 0, stream>>>(cnt, offs, bsum, n_nodes);
    scan_b_kernel<<<1, 256, 0, stream>>>(bsum, nblk);
    scan_c_kernel<<<(n_nodes + 255) / 256, 256, 0, stream>>>(offs, cursor, bsum, n_nodes);

    scatter_kernel<<<eblocks, 256, 0, stream>>>(src, dst, etype, norm, cursor, rec, n_edges);

    gather_kernel<<<(n_nodes + GN - 1) / GN, 256, 0, stream>>>(
        rec, offs, xb, comp_l, bias_l, features, out, n_nodes, n_edges);
}

// Round 7
// 230.175 us; speedup vs baseline: 2.1938x; 2.1938x over previous
//
#include <hip/hip_runtime.h>

#define HD   64
#define NB   4
#define PROJ 256   // HD * NB columns
#define SCAN_BLK 1024

typedef __attribute__((ext_vector_type(8))) short bf16x8;
typedef __attribute__((ext_vector_type(4))) float f32x4;
typedef __attribute__((ext_vector_type(8))) unsigned short u16x8;

__device__ __forceinline__ float bf2f(unsigned short u) {
    union { unsigned int i; float f; } c; c.i = ((unsigned int)u) << 16; return c.f;
}
__device__ __forceinline__ unsigned short f2bf(float f) {
    union { float f; unsigned int i; } c; c.f = f;
    unsigned int r = c.i + 0x7FFF + ((c.i >> 16) & 1);   // round-to-nearest-even
    return (unsigned short)(r >> 16);
}

// ---- W pre-pack: A-operand fragments for the swapped MFMA ----
__global__ __launch_bounds__(256) void wpack_kernel(
    const float* __restrict__ Vl, unsigned short* __restrict__ wpack) {
    int t = threadIdx.x;
#pragma unroll
    for (int i = 0; i < 8; ++i) {
        int s = t + i * 256;            // 0..2047 lane-slots
        int lane = s & 63;
        int ksct = s >> 6;
        int ks = ksct & 1, ct = ksct >> 1;
        int c = ct * 16 + (lane & 15);
        int o = c >> 2, b = c & 3;
        unsigned int w[4];
#pragma unroll
        for (int j = 0; j < 4; ++j) {
            int k0 = ks * 32 + ((lane >> 4) & 3) * 8 + 2 * j;
            unsigned short lo = f2bf(Vl[((size_t)b * HD + k0) * HD + o]);
            unsigned short hi = f2bf(Vl[((size_t)b * HD + k0 + 1) * HD + o]);
            w[j] = (unsigned)lo | ((unsigned)hi << 16);
        }
        uint4 st = make_uint4(w[0], w[1], w[2], w[3]);
        *(uint4*)(wpack + (size_t)s * 8) = st;
    }
}

// ---- MFMA projection: xb[n][c] (bf16) = sum_k f[n][k] * W[k][c] ----
#define FS_STRIDE 72
__global__ __launch_bounds__(256, 4) void proj_mfma_kernel(
    const float* __restrict__ f, const unsigned short* __restrict__ wpack,
    unsigned short* __restrict__ xb, int n_nodes) {
    __shared__ unsigned short fs[64 * FS_STRIDE];
    int t = threadIdx.x;
    int lane = t & 63;
    int wt = t >> 6;
    int n0 = blockIdx.x * 64;

#pragma unroll
    for (int i = 0; i < 4; ++i) {
        int idx = t + i * 256;
        int node = idx >> 4;
        int kg = idx & 15;
        unsigned int lo = 0, hi = 0;
        if (n0 + node < n_nodes) {
            float4 v = *(const float4*)(f + ((size_t)(n0 + node) * HD + kg * 4));
            lo = (unsigned)f2bf(v.x) | ((unsigned)f2bf(v.y) << 16);
            hi = (unsigned)f2bf(v.z) | ((unsigned)f2bf(v.w) << 16);
        }
        *(uint2*)(fs + node * FS_STRIDE + kg * 4) = make_uint2(lo, hi);
    }
    __syncthreads();

    bf16x8 bfr[2];
#pragma unroll
    for (int ks = 0; ks < 2; ++ks) {
        int off = (wt * 16 + (lane & 15)) * FS_STRIDE + ks * 32 + ((lane >> 4) & 3) * 8;
        bfr[ks] = *reinterpret_cast<const bf16x8*>(&fs[off]);
    }

    f32x4 acc[16];
#pragma unroll
    for (int ct = 0; ct < 16; ++ct) acc[ct] = (f32x4){0.f, 0.f, 0.f, 0.f};

#pragma unroll
    for (int ct = 0; ct < 16; ++ct) {
#pragma unroll
        for (int ks = 0; ks < 2; ++ks) {
            bf16x8 a = *reinterpret_cast<const bf16x8*>(
                wpack + ((size_t)(ct * 2 + ks) * 64 + lane) * 8);
            acc[ct] = __builtin_amdgcn_mfma_f32_16x16x32_bf16(a, bfr[ks], acc[ct], 0, 0, 0);
        }
    }

    int node = n0 + wt * 16 + (lane & 15);
    if (node < n_nodes) {
#pragma unroll
        for (int ct = 0; ct < 16; ++ct) {
            int c0 = ct * 16 + ((lane >> 4) & 3) * 4;
            unsigned int lo = (unsigned)f2bf(acc[ct][0]) | ((unsigned)f2bf(acc[ct][1]) << 16);
            unsigned int hi = (unsigned)f2bf(acc[ct][2]) | ((unsigned)f2bf(acc[ct][3]) << 16);
            *(uint2*)(xb + (size_t)node * PROJ + c0) = make_uint2(lo, hi);
        }
    }
}

// ---- CSR build: histogram -> exclusive scan -> scatter ----

__global__ __launch_bounds__(256) void hist_kernel(
    const int* __restrict__ dst, int* __restrict__ cnt, int n_edges) {
    int e = blockIdx.x * 256 + threadIdx.x;
    if (e < n_edges) atomicAdd(&cnt[dst[e]], 1);
}

__global__ __launch_bounds__(256) void scan_a_kernel(
    const int* __restrict__ cnt, int* __restrict__ offs,
    int* __restrict__ bsum, int n) {
    __shared__ int sd[256];
    int t = threadIdx.x;
    int base = blockIdx.x * SCAN_BLK + t * 4;
    int v[4];
#pragma unroll
    for (int j = 0; j < 4; ++j) v[j] = (base + j < n) ? cnt[base + j] : 0;
    int s = v[0] + v[1] + v[2] + v[3];
    sd[t] = s; __syncthreads();
    for (int off = 1; off < 256; off <<= 1) {
        int x = (t >= off) ? sd[t - off] : 0;
        __syncthreads();
        sd[t] += x;
        __syncthreads();
    }
    int excl = sd[t] - s;
    if (t == 255) bsum[blockIdx.x] = sd[t];
    int run = excl;
#pragma unroll
    for (int j = 0; j < 4; ++j) {
        if (base + j < n) offs[base + j] = run;
        run += v[j];
    }
}

__global__ __launch_bounds__(256) void scan_b_kernel(int* __restrict__ bsum, int nblk) {
    __shared__ int sd[256];
    int t = threadIdx.x;
    int s = (t < nblk) ? bsum[t] : 0;
    sd[t] = s; __syncthreads();
    for (int off = 1; off < 256; off <<= 1) {
        int x = (t >= off) ? sd[t - off] : 0;
        __syncthreads();
        sd[t] += x;
        __syncthreads();
    }
    if (t < nblk) bsum[t] = sd[t] - s;
}

__global__ __launch_bounds__(256) void scan_c_kernel(
    int* __restrict__ offs, int* __restrict__ cursor,
    const int* __restrict__ bsum, int n) {
    int i = blockIdx.x * 256 + threadIdx.x;
    if (i < n) {
        int v = offs[i] + bsum[i / SCAN_BLK];
        offs[i] = v;
        cursor[i] = v;
    }
}

// pack {src(0:19) | etype(20:24), norm_bits}
__global__ __launch_bounds__(256) void scatter_kernel(
    const int* __restrict__ src, const int* __restrict__ dst,
    const int* __restrict__ etype, const float* __restrict__ norm,
    int* __restrict__ cursor, uint2* __restrict__ rec, int n_edges) {
    int e = blockIdx.x * 256 + threadIdx.x;
    if (e >= n_edges) return;
    int d = dst[e];
    int pos = atomicAdd(&cursor[d], 1);
    uint2 rr;
    rr.x = (unsigned)src[e] | ((unsigned)etype[e] << 20);
    rr.y = __float_as_uint(norm[e]);
    rec[pos] = rr;
}

// ---- segmented sum: one dst per 32-lane half-wave, register accumulate ----
// lane32 covers columns c = lane32*8 + j (j=0..7): o = 2*lane32 + (j>>2), b = j&3
__global__ __launch_bounds__(256) void seg2_kernel(
    const uint2* __restrict__ rec, const int* __restrict__ offs,
    const unsigned short* __restrict__ xb,
    const float* __restrict__ comp_l, const float* __restrict__ bias_l,
    const float* __restrict__ f, float* __restrict__ out,
    int n_nodes, int n_edges) {
    int d = blockIdx.x * 8 + (threadIdx.x >> 5);
    if (d >= n_nodes) return;
    int l32 = threadIdx.x & 31;
    int start = offs[d];
    int end = (d + 1 < n_nodes) ? offs[d + 1] : n_edges;
    int deg = end - start;
    const uint2* r = rec + start;
    float a0 = 0.f, a1 = 0.f;
    int k = 0;
    for (; k + 3 < deg; k += 4) {
        uint2 q0 = r[k], q1 = r[k+1], q2 = r[k+2], q3 = r[k+3];  // 32B contiguous
        u16x8 v0 = ((const u16x8*)(xb + (size_t)(q0.x & 0xFFFFF) * PROJ))[l32];
        u16x8 v1 = ((const u16x8*)(xb + (size_t)(q1.x & 0xFFFFF) * PROJ))[l32];
        u16x8 v2 = ((const u16x8*)(xb + (size_t)(q2.x & 0xFFFFF) * PROJ))[l32];
        u16x8 v3 = ((const u16x8*)(xb + (size_t)(q3.x & 0xFFFFF) * PROJ))[l32];
        float4 c0 = *(const float4*)(comp_l + ((q0.x >> 20) & 31) * NB);
        float4 c1 = *(const float4*)(comp_l + ((q1.x >> 20) & 31) * NB);
        float4 c2 = *(const float4*)(comp_l + ((q2.x >> 20) & 31) * NB);
        float4 c3 = *(const float4*)(comp_l + ((q3.x >> 20) & 31) * NB);
        float n0 = __uint_as_float(q0.y), n1 = __uint_as_float(q1.y);
        float n2 = __uint_as_float(q2.y), n3 = __uint_as_float(q3.y);
        a0 += n0 * (c0.x*bf2f(v0[0]) + c0.y*bf2f(v0[1]) + c0.z*bf2f(v0[2]) + c0.w*bf2f(v0[3]));
        a1 += n0 * (c0.x*bf2f(v0[4]) + c0.y*bf2f(v0[5]) + c0.z*bf2f(v0[6]) + c0.w*bf2f(v0[7]));
        a0 += n1 * (c1.x*bf2f(v1[0]) + c1.y*bf2f(v1[1]) + c1.z*bf2f(v1[2]) + c1.w*bf2f(v1[3]));
        a1 += n1 * (c1.x*bf2f(v1[4]) + c1.y*bf2f(v1[5]) + c1.z*bf2f(v1[6]) + c1.w*bf2f(v1[7]));
        a0 += n2 * (c2.x*bf2f(v2[0]) + c2.y*bf2f(v2[1]) + c2.z*bf2f(v2[2]) + c2.w*bf2f(v2[3]));
        a1 += n2 * (c2.x*bf2f(v2[4]) + c2.y*bf2f(v2[5]) + c2.z*bf2f(v2[6]) + c2.w*bf2f(v2[7]));
        a0 += n3 * (c3.x*bf2f(v3[0]) + c3.y*bf2f(v3[1]) + c3.z*bf2f(v3[2]) + c3.w*bf2f(v3[3]));
        a1 += n3 * (c3.x*bf2f(v3[4]) + c3.y*bf2f(v3[5]) + c3.z*bf2f(v3[6]) + c3.w*bf2f(v3[7]));
    }
    for (; k < deg; ++k) {
        uint2 q = r[k];
        u16x8 v = ((const u16x8*)(xb + (size_t)(q.x & 0xFFFFF) * PROJ))[l32];
        float4 c = *(const float4*)(comp_l + ((q.x >> 20) & 31) * NB);
        float nn = __uint_as_float(q.y);
        a0 += nn * (c.x*bf2f(v[0]) + c.y*bf2f(v[1]) + c.z*bf2f(v[2]) + c.w*bf2f(v[3]));
        a1 += nn * (c.x*bf2f(v[4]) + c.y*bf2f(v[5]) + c.z*bf2f(v[6]) + c.w*bf2f(v[7]));
    }
    // epilogue: o = 2*l32, 2*l32+1; coalesced float2 store
    int o = 2 * l32;
    size_t ob = (size_t)d * HD + o;
    float r0 = fmaxf(a0 + bias_l[o],     0.f) + f[ob];
    float r1 = fmaxf(a1 + bias_l[o + 1], 0.f) + f[ob + 1];
    *(float2*)(out + ob) = make_float2(r0, r1);
}

extern "C" void kernel_launch(void* const* d_in, const int* in_sizes, int n_in,
                              void* d_out, int out_size, void* d_ws, size_t ws_size,
                              hipStream_t stream) {
    const float* features = (const float*)d_in[0];
    const float* norm     = (const float*)d_in[1];
    const float* V        = (const float*)d_in[2];
    const float* comp     = (const float*)d_in[3];
    const float* bias     = (const float*)d_in[4];
    const int*   src      = (const int*)d_in[5];
    const int*   dst      = (const int*)d_in[6];
    const int*   etype    = (const int*)d_in[7];
    float* out = (float*)d_out;

    int n_nodes = in_sizes[0] / HD;
    int n_edges = in_sizes[5];
    int L       = in_sizes[2] / (NB * HD * HD);   // N_HID
    int l       = L - 1;                          // only the last layer survives
    int comp_stride = in_sizes[3] / L;            // NUM_RELS * NB

    const float* Vl     = V    + (size_t)l * NB * HD * HD;
    const float* comp_l = comp + (size_t)l * comp_stride;
    const float* bias_l = bias + (size_t)l * HD;

    // workspace carve-up
    char* ws = (char*)d_ws;
    unsigned short* xb = (unsigned short*)ws;                 // bf16 [n_nodes, 256]
    size_t off = (size_t)n_nodes * PROJ * sizeof(unsigned short);
    int* cnt    = (int*)(ws + off);  off += (size_t)n_nodes * sizeof(int);
    int* offs   = (int*)(ws + off);  off += (size_t)n_nodes * sizeof(int);
    int* cursor = (int*)(ws + off);  off += (size_t)n_nodes * sizeof(int);
    int* bsum   = (int*)(ws + off);  off += 1024 * sizeof(int);
    unsigned short* wpack = (unsigned short*)(ws + off); off += 2048 * 8 * sizeof(unsigned short);
    off = (off + 7) & ~(size_t)7;
    uint2* rec  = (uint2*)(ws + off);                         // [n_edges]

    hipMemsetAsync(cnt, 0, (size_t)n_nodes * sizeof(int), stream);

    wpack_kernel<<<1, 256, 0, stream>>>(Vl, wpack);
    proj_mfma_kernel<<<(n_nodes + 63) / 64, 256, 0, stream>>>(features, wpack, xb, n_nodes);

    int eblocks = (n_edges + 255) / 256;
    hist_kernel<<<eblocks, 256, 0, stream>>>(dst, cnt, n_edges);

    int nblk = (n_nodes + SCAN_BLK - 1) / SCAN_BLK;           // <= 256
    scan_a_kernel<<<nblk, 256, 0, stream>>>(cnt, offs, bsum, n_nodes);
    scan_b_kernel<<<1, 256, 0, stream>>>(bsum, nblk);
    scan_c_kernel<<<(n_nodes + 255) / 256, 256, 0, stream>>>(offs, cursor, bsum, n_nodes);

    scatter_kernel<<<eblocks, 256, 0, stream>>>(src, dst, etype, norm, cursor, rec, n_edges);

    seg2_kernel<<<(n_nodes + 7) / 8, 256, 0, stream>>>(
        rec, offs, xb, comp_l, bias_l, features, out, n_nodes, n_edges);
}